// Round 1
// baseline (930.545 us; speedup 1.0000x reference)
//
#include <hip/hip_runtime.h>
#include <hip/hip_bf16.h>

// Problem constants (match reference)
#define N_UE 100000
#define N_AP 10000
#define N_E  1600000
#define DD   64
#define HH   128

typedef float f32x4 __attribute__((ext_vector_type(4)));
typedef short s8b   __attribute__((ext_vector_type(8)));
typedef short s4b   __attribute__((ext_vector_type(4)));

static __device__ __forceinline__ unsigned short f2bf(float x) {
  union { float f; unsigned int u; } v; v.f = x;
  unsigned int r = v.u + 0x7fffu + ((v.u >> 16) & 1u);  // RTN-even
  return (unsigned short)(r >> 16);
}
static __device__ __forceinline__ float bf2f(unsigned short b) {
  union { unsigned int u; float f; } v; v.u = ((unsigned int)b) << 16;
  return v.f;
}

// K0: WT[n][k] = bf16(W1a[k][n]) for k<64 (edge-half of W1a, transposed for B-frag reads);
//     zero the histogram counters.
__global__ void apk0_prep(const float* __restrict__ W1a, short* __restrict__ WTg,
                          int* __restrict__ counts) {
  int i = blockIdx.x * 256 + threadIdx.x;
  int n = gridDim.x * 256;
  for (int x = i; x < 128 * 64; x += n) {
    int col = x >> 6, k = x & 63;
    WTg[x] = (short)f2bf(W1a[k * 128 + col]);   // WTg[col*64 + k]
  }
  for (int x = i; x < N_AP; x += n) counts[x] = 0;
}

// K1: U[u][j] = bf16( ue_hid[u] @ W1a[64:128] + b1a )   [100000 x 128], bf16
__global__ __launch_bounds__(256) void apk1_ueproj(
    const float* __restrict__ ue_hid, const float* __restrict__ W1a,
    const float* __restrict__ b1a, unsigned short* __restrict__ U) {
  __shared__ float rows[16][64];
  int t = threadIdx.x;
  int base = blockIdx.x * 16;
  {
    int r = t >> 4, seg = t & 15;
    ((float4*)&rows[r][seg * 4])[0] =
        ((const float4*)(ue_hid + (size_t)(base + r) * 64))[seg];
  }
  __syncthreads();
  int j = t & 127, half = t >> 7;
  float acc[8] = {0, 0, 0, 0, 0, 0, 0, 0};
  for (int k = 0; k < 64; k++) {
    float w = W1a[(64 + k) * 128 + j];
    for (int r = 0; r < 8; r++) acc[r] += rows[half * 8 + r][k] * w;
  }
  float bb = b1a[j];
  for (int r = 0; r < 8; r++)
    U[(size_t)(base + half * 8 + r) * 128 + j] = f2bf(acc[r] + bb);
}

// K2: histogram of dst
__global__ void apk2_hist(const int* __restrict__ dst, int* __restrict__ counts) {
  int i = blockIdx.x * blockDim.x + threadIdx.x;
  int stride = gridDim.x * blockDim.x;
  for (; i < N_E; i += stride) atomicAdd(&counts[dst[i]], 1);
}

// K3: exclusive scan of counts -> offsets[10001]; cursor = offsets copy
__global__ __launch_bounds__(256) void apk3_scan(const int* __restrict__ counts,
                                                 int* __restrict__ offsets,
                                                 int* __restrict__ cursor) {
  __shared__ int p[256];
  int t = threadIdx.x;
  const int CH = 40;  // 256*40 >= 10000
  int start = t * CH, end = min(start + CH, N_AP);
  int s = 0;
  for (int i = start; i < end; i++) s += counts[i];
  p[t] = s;
  __syncthreads();
  for (int d = 1; d < 256; d <<= 1) {
    int v = p[t] + ((t >= d) ? p[t - d] : 0);
    __syncthreads();
    p[t] = v;
    __syncthreads();
  }
  int base = (t == 0) ? 0 : p[t - 1];
  for (int i = start; i < end; i++) {
    offsets[i] = base;
    cursor[i] = base;
    base += counts[i];
  }
  if (t == 255) offsets[N_AP] = base;  // == N_E
}

// K4: scatter edge ids (and their src) into dst-sorted order
__global__ void apk4_scatter(const int* __restrict__ dst, const int* __restrict__ src,
                             int* __restrict__ cursor, int* __restrict__ order,
                             int* __restrict__ srcs) {
  int i = blockIdx.x * blockDim.x + threadIdx.x;
  int stride = gridDim.x * blockDim.x;
  for (; i < N_E; i += stride) {
    int d = dst[i];
    int pos = atomicAdd(&cursor[d], 1);
    order[pos] = i;
    srcs[pos] = src[i];
  }
}

// K5: per-AP: aggW[a] = sum over edges e of relu(edge_hid[e] @ W1a_top + U[src[e]])
// One block (256 thr = 4 waves) per AP; 16-edge chunks; mfma 16x16x32 bf16.
__global__ __launch_bounds__(256) void apk5_edges(
    const float* __restrict__ edge_hid, const unsigned short* __restrict__ U,
    const short* __restrict__ WTg, const int* __restrict__ offsets,
    const int* __restrict__ order, const int* __restrict__ srcs,
    float* __restrict__ aggW) {
  __shared__ short WT[128][72];          // B operand, [n][k], padded (144B rows)
  __shared__ short Ae[16][72];           // A operand, [edge][k], bf16, padded
  __shared__ unsigned short Ub[16][136]; // gathered U rows, bf16, padded
  __shared__ int eids[16];
  __shared__ int esrc[16];
  int t = threadIdx.x;
  int a = blockIdx.x;
  int wave = t >> 6, lane = t & 63;
  int quad = lane >> 4, l16 = lane & 15;
  // stage WT (128x64 bf16 = 8192 shorts = 1024 x short8)
  for (int i = t; i < 1024; i += 256) {
    int n = i >> 3, seg = i & 7;
    *(s8b*)&WT[n][seg * 8] = ((const s8b*)WTg)[i];
  }
  int start = offsets[a], end = offsets[a + 1];
  float accs0[4] = {0, 0, 0, 0}, accs1[4] = {0, 0, 0, 0};
  int col0 = wave * 32, col1 = wave * 32 + 16;
  for (int c = start; c < end; c += 16) {
    int nv = end - c; if (nv > 16) nv = 16;
    __syncthreads();  // prev chunk's LDS reads done (also covers WT on iter 0)
    if (t < 16) {
      int valid = (t < nv);
      eids[t] = valid ? order[c + t] : -1;
      esrc[t] = valid ? srcs[c + t] : -1;
    }
    __syncthreads();
    {
      int row = t >> 4, seg = t & 15;
      int e = eids[row];
      float4 v = make_float4(0.f, 0.f, 0.f, 0.f);
      uint4 uv = make_uint4(0u, 0u, 0u, 0u);
      if (e >= 0) {
        v  = ((const float4*)(edge_hid + (size_t)e * 64))[seg];
        uv = ((const uint4*)(U + (size_t)esrc[row] * 128))[seg];
      }
      s4b b4;
      b4[0] = (short)f2bf(v.x); b4[1] = (short)f2bf(v.y);
      b4[2] = (short)f2bf(v.z); b4[3] = (short)f2bf(v.w);
      *(s4b*)&Ae[row][seg * 4] = b4;
      *(uint4*)&Ub[row][seg * 8] = uv;
    }
    __syncthreads();
    s8b a0  = *(const s8b*)&Ae[l16][quad * 8];
    s8b a1  = *(const s8b*)&Ae[l16][32 + quad * 8];
    s8b b00 = *(const s8b*)&WT[col0 + l16][quad * 8];
    s8b b01 = *(const s8b*)&WT[col0 + l16][32 + quad * 8];
    s8b b10 = *(const s8b*)&WT[col1 + l16][quad * 8];
    s8b b11 = *(const s8b*)&WT[col1 + l16][32 + quad * 8];
    f32x4 c0 = {0.f, 0.f, 0.f, 0.f}, c1 = {0.f, 0.f, 0.f, 0.f};
    c0 = __builtin_amdgcn_mfma_f32_16x16x32_bf16(a0, b00, c0, 0, 0, 0);
    c0 = __builtin_amdgcn_mfma_f32_16x16x32_bf16(a1, b01, c0, 0, 0, 0);
    c1 = __builtin_amdgcn_mfma_f32_16x16x32_bf16(a0, b10, c1, 0, 0, 0);
    c1 = __builtin_amdgcn_mfma_f32_16x16x32_bf16(a1, b11, c1, 0, 0, 0);
    for (int r = 0; r < 4; r++) {
      int qr = quad * 4 + r;  // C row = edge-in-chunk
      float u0 = bf2f(Ub[qr][col0 + l16]);
      float u1 = bf2f(Ub[qr][col1 + l16]);
      accs0[r] += fmaxf(c0[r] + u0, 0.f);  // padded rows: relu(0+0)=0
      accs1[r] += fmaxf(c1[r] + u1, 0.f);
    }
  }
  float s0 = accs0[0] + accs0[1] + accs0[2] + accs0[3];
  float s1 = accs1[0] + accs1[1] + accs1[2] + accs1[3];
  s0 += __shfl_xor(s0, 16); s0 += __shfl_xor(s0, 32);
  s1 += __shfl_xor(s1, 16); s1 += __shfl_xor(s1, 32);
  if (quad == 0) {
    aggW[(size_t)a * 128 + col0 + l16] = s0;
    aggW[(size_t)a * 128 + col1 + l16] = s1;
  }
}

// K6: per 16 APs: Y = aggW@W1b + cnt*b1b;  T = relu([ap_hid,Y]@W2a + b2a);
//     out = T@W2b + b2b.  All fp32, weights staged through a 32KB LDS buffer.
__global__ __launch_bounds__(256) void apk6_mlp2(
    const float* __restrict__ ap_hid, const float* __restrict__ W1b,
    const float* __restrict__ b1b, const float* __restrict__ W2a,
    const float* __restrict__ b2a, const float* __restrict__ W2b,
    const float* __restrict__ b2b, const float* __restrict__ aggW,
    const int* __restrict__ offsets, float* __restrict__ out) {
  __shared__ float wbuf[64 * 128];   // 32KB weight tile
  __shared__ float zrows[16 * 128];  // agg rows, later reused as T
  __shared__ float yrows[16 * 128];
  __shared__ float arows[16 * 64];
  __shared__ float cbuf[16];
  int t = threadIdx.x;
  int apb = blockIdx.x * 16;
  for (int i = t; i < 16 * 128 / 4; i += 256)
    ((float4*)zrows)[i] = ((const float4*)(aggW + (size_t)apb * 128))[i];
  for (int i = t; i < 16 * 64 / 4; i += 256)
    ((float4*)arows)[i] = ((const float4*)(ap_hid + (size_t)apb * 64))[i];
  if (t < 16) cbuf[t] = (float)(offsets[apb + t + 1] - offsets[apb + t]);
  int j = t & 127, half = t >> 7;
  // ---- phase 1: Y = agg @ W1b + cnt*b1b
  {
    float bb = b1b[j];
    __syncthreads();
    float acc[8];
    for (int r = 0; r < 8; r++) acc[r] = cbuf[half * 8 + r] * bb;
    for (int p = 0; p < 2; p++) {
      __syncthreads();
      for (int i = t; i < 64 * 128 / 4; i += 256)
        ((float4*)wbuf)[i] = ((const float4*)(W1b + p * 64 * 128))[i];
      __syncthreads();
      for (int k = 0; k < 64; k++) {
        float w = wbuf[k * 128 + j];
        for (int r = 0; r < 8; r++)
          acc[r] += zrows[(half * 8 + r) * 128 + (p * 64 + k)] * w;
      }
    }
    for (int r = 0; r < 8; r++) yrows[(half * 8 + r) * 128 + j] = acc[r];
  }
  // ---- phase 2: T = relu([ap, Y] @ W2a + b2a), stored into zrows
  {
    float acc2[8];
    float bb = b2a[j];
    for (int r = 0; r < 8; r++) acc2[r] = bb;
    __syncthreads();
    for (int i = t; i < 64 * 128 / 4; i += 256)
      ((float4*)wbuf)[i] = ((const float4*)W2a)[i];
    __syncthreads();
    for (int k = 0; k < 64; k++) {
      float w = wbuf[k * 128 + j];
      for (int r = 0; r < 8; r++) acc2[r] += arows[(half * 8 + r) * 64 + k] * w;
    }
    for (int p = 0; p < 2; p++) {
      __syncthreads();
      for (int i = t; i < 64 * 128 / 4; i += 256)
        ((float4*)wbuf)[i] = ((const float4*)(W2a + (64 + p * 64) * 128))[i];
      __syncthreads();
      for (int k = 0; k < 64; k++) {
        float w = wbuf[k * 128 + j];
        for (int r = 0; r < 8; r++)
          acc2[r] += yrows[(half * 8 + r) * 128 + (p * 64 + k)] * w;
      }
    }
    __syncthreads();
    for (int r = 0; r < 8; r++)
      zrows[(half * 8 + r) * 128 + j] = fmaxf(acc2[r], 0.f);
  }
  // ---- phase 3: out = T @ W2b + b2b
  {
    __syncthreads();
    for (int i = t; i < 128 * 64 / 4; i += 256)
      ((float4*)wbuf)[i] = ((const float4*)W2b)[i];
    __syncthreads();
    int i2 = t & 63, q = t >> 6;
    float acc3[4];
    float bb = b2b[i2];
    for (int r = 0; r < 4; r++) acc3[r] = bb;
    for (int k = 0; k < 128; k++) {
      float w = wbuf[k * 64 + i2];
      for (int r = 0; r < 4; r++) acc3[r] += zrows[(q * 4 + r) * 128 + k] * w;
    }
    for (int r = 0; r < 4; r++)
      out[(size_t)(apb + q * 4 + r) * 64 + i2] = acc3[r];
  }
}

extern "C" void kernel_launch(void* const* d_in, const int* in_sizes, int n_in,
                              void* d_out, int out_size, void* d_ws, size_t ws_size,
                              hipStream_t stream) {
  const float* ue_hid   = (const float*)d_in[0];
  const float* ap_hid   = (const float*)d_in[1];
  const float* edge_hid = (const float*)d_in[2];
  const int*   src      = (const int*)d_in[3];
  const int*   dst      = (const int*)d_in[4];
  const float* W1a      = (const float*)d_in[5];
  const float* b1a      = (const float*)d_in[6];
  const float* W1b      = (const float*)d_in[7];
  const float* b1b      = (const float*)d_in[8];
  const float* W2a      = (const float*)d_in[9];
  const float* b2a      = (const float*)d_in[10];
  const float* W2b      = (const float*)d_in[11];
  const float* b2b      = (const float*)d_in[12];
  float* out = (float*)d_out;

  unsigned char* ws = (unsigned char*)d_ws;
  unsigned short* U = (unsigned short*)(ws);              // 25,600,000 B
  short* WTg        = (short*)(ws + 25600000);            //     16,384 B
  int* counts       = (int*)(ws + 25616384);              //     40,192 B (padded)
  int* offsets      = (int*)(ws + 25656576);              //     40,192 B
  int* cursor       = (int*)(ws + 25696768);              //     40,192 B
  int* order        = (int*)(ws + 25736960);              //  6,400,000 B
  int* srcs         = (int*)(ws + 32136960);              //  6,400,000 B
  float* aggW       = (float*)(ws + 38536960);            //  5,120,000 B
  // total: 43,656,960 B of d_ws

  apk0_prep<<<40, 256, 0, stream>>>(W1a, WTg, counts);
  apk1_ueproj<<<N_UE / 16, 256, 0, stream>>>(ue_hid, W1a, b1a, U);
  apk2_hist<<<2048, 256, 0, stream>>>(dst, counts);
  apk3_scan<<<1, 256, 0, stream>>>(counts, offsets, cursor);
  apk4_scatter<<<2048, 256, 0, stream>>>(dst, src, cursor, order, srcs);
  apk5_edges<<<N_AP, 256, 0, stream>>>(edge_hid, U, WTg, offsets, order, srcs, aggW);
  apk6_mlp2<<<N_AP / 16, 256, 0, stream>>>(ap_hid, W1b, b1b, W2a, b2a, W2b, b2b,
                                           aggW, offsets, out);
}